// Round 3
// baseline (530.303 us; speedup 1.0000x reference)
//
#include <hip/hip_runtime.h>
#include <cstdint>
#include <cstddef>

typedef __attribute__((ext_vector_type(4))) float f32x4;
typedef __attribute__((ext_vector_type(8))) __bf16 bf16x8;
typedef __attribute__((ext_vector_type(8))) short short8;

__device__ __forceinline__ unsigned short f2bf(float f) {
  unsigned u = __builtin_bit_cast(unsigned, f);
  u += 0x7FFFu + ((u >> 16) & 1u);  // RNE
  return (unsigned short)(u >> 16);
}
__device__ __forceinline__ unsigned pack2(float a, float b) {
  return (unsigned)f2bf(a) | ((unsigned)f2bf(b) << 16);
}
__device__ __forceinline__ void async16(const void* g, void* l) {
  __builtin_amdgcn_global_load_lds((const __attribute__((address_space(1))) unsigned int*)g,
                                   (__attribute__((address_space(3))) unsigned int*)l, 16, 0, 0);
}
__device__ __forceinline__ bf16x8 ldsFrag(const unsigned short* p) {
  return __builtin_bit_cast(bf16x8, *(const short8*)p);
}

// ---------------------------------------------------------------------------
// GEMM: C[128,N] = A[128,K](bf16) @ W[N,K](fp32)^T + bias
// A: global_load_lds into XOR-swizzled LDS (16B chunks, cc = c ^ (r&7)),
//    double-buffered, distance-1.
// W: distance-2 register prefetch -> convert -> LDS double buffer.
// EPI 0: fp32 store. EPI 1: tanh -> bf16 store.
// ---------------------------------------------------------------------------
template <int BN, int WAVES_M, int WAVES_N, int EPI>
__global__ __launch_bounds__(256, 4) void gemm_bt(const unsigned short* __restrict__ A,
                                                  const float* __restrict__ W,
                                                  const float* __restrict__ bias,
                                                  void* __restrict__ Cout,
                                                  int lda, int ldw, int N, int K) {
  constexpr int WM = 128 / WAVES_M, WN = BN / WAVES_N;
  constexpr int MT = WM / 16, NT = WN / 16;
  constexpr int WCH = (BN == 32) ? 2 : 1;  // f32x4 chunks per thread per W tile
  __shared__ unsigned short a_lds[2][128 * 64];
  __shared__ unsigned short w_lds[2][BN * 64];

  const int tid = threadIdx.x;
  const int wave = tid >> 6, lane = tid & 63;
  const int quad = lane >> 4, l16 = lane & 15;
  const int n0 = blockIdx.x * BN;
  const int wm = (wave / WAVES_N) * WM, wn = (wave % WAVES_N) * WN;
  const int niter = K >> 6;

  f32x4 wv[2][WCH];

  auto stageA = [&](int k0, int buf) {
#pragma unroll
    for (int i = 0; i < 4; ++i) {
      int chunk = (wave * 4 + i) * 64 + lane;  // 1024 = 128 rows x 8 chunks
      int r = chunk >> 3;
      int c = (chunk & 7) ^ (r & 7);
      async16(A + (size_t)r * lda + k0 + c * 8, &a_lds[buf][chunk * 8]);
    }
  };
  auto loadW = [&](int k0, int set) {
    if constexpr (BN == 32) {
      const float* p = W + (size_t)(n0 + (tid >> 3)) * ldw + k0 + (tid & 7) * 8;
      wv[set][0] = *(const f32x4*)p;
      wv[set][1] = *(const f32x4*)(p + 4);
    } else {
      const float* p = W + (size_t)(n0 + (tid >> 4)) * ldw + k0 + ((tid >> 1) & 7) * 8 + (tid & 1) * 4;
      wv[set][0] = *(const f32x4*)p;
    }
  };
  auto writeW = [&](int set, int buf) {
    if constexpr (BN == 32) {
      int wr = tid >> 3, wc = tid & 7;
      uint4 pk{pack2(wv[set][0].x, wv[set][0].y), pack2(wv[set][0].z, wv[set][0].w),
               pack2(wv[set][1].x, wv[set][1].y), pack2(wv[set][1].z, wv[set][1].w)};
      *(uint4*)&w_lds[buf][(wr * 8 + (wc ^ (wr & 7))) * 8] = pk;
    } else {
      int wr = tid >> 4, wc = (tid >> 1) & 7, half = tid & 1;
      uint2 pk{pack2(wv[set][0].x, wv[set][0].y), pack2(wv[set][0].z, wv[set][0].w)};
      *(uint2*)&w_lds[buf][(wr * 8 + (wc ^ (wr & 7))) * 8 + half * 4] = pk;
    }
  };

  f32x4 acc[MT][NT] = {};

  // prologue: A tile0 (dist-1), W tiles 0,1 (dist-2)
  loadW(0, 0);
  stageA(0, 0);
  loadW(64, 1);
  writeW(0, 0);
  __syncthreads();

  for (int ki = 0; ki < niter; ++ki) {
    const int cur = ki & 1;
    if (ki + 1 < niter) stageA((ki + 1) * 64, cur ^ 1);
    if (ki + 2 < niter) loadW((ki + 2) * 64, cur);
#pragma unroll
    for (int kh = 0; kh < 2; ++kh) {
      const int c = kh * 4 + quad;
      bf16x8 af[MT], wf[NT];
#pragma unroll
      for (int mt = 0; mt < MT; ++mt) {
        int m = wm + mt * 16 + l16;
        af[mt] = ldsFrag(&a_lds[cur][(m * 8 + (c ^ (m & 7))) * 8]);
      }
#pragma unroll
      for (int nt = 0; nt < NT; ++nt) {
        int n = wn + nt * 16 + l16;
        wf[nt] = ldsFrag(&w_lds[cur][(n * 8 + (c ^ (n & 7))) * 8]);
      }
#pragma unroll
      for (int mt = 0; mt < MT; ++mt)
#pragma unroll
        for (int nt = 0; nt < NT; ++nt)
          acc[mt][nt] = __builtin_amdgcn_mfma_f32_16x16x32_bf16(af[mt], wf[nt], acc[mt][nt], 0, 0, 0);
    }
    if (ki + 1 < niter) writeW(cur ^ 1, cur ^ 1);
    __syncthreads();
  }

#pragma unroll
  for (int mt = 0; mt < MT; ++mt)
#pragma unroll
    for (int nt = 0; nt < NT; ++nt) {
      int n = n0 + wn + nt * 16 + l16;
      float bv = bias[n];
#pragma unroll
      for (int r = 0; r < 4; ++r) {
        int m = wm + mt * 16 + quad * 4 + r;
        float val = acc[mt][nt][r] + bv;
        if constexpr (EPI == 0) {
          ((float*)Cout)[(size_t)m * N + n] = val;
        } else {
          ((unsigned short*)Cout)[(size_t)m * N + n] = f2bf(tanhf(val));
        }
      }
    }
}

// ---------------------------------------------------------------------------
// Fused GRU layer: h' = (1-z)*n + z*h  in one kernel (GEMMs + gates).
// Block = 16 j-columns x 64 m-rows. 4 accumulators:
//   aR = x.Wih_r + h.Whh_r ; aZ = x.Wih_z + h.Whh_z ; aNi = x.Wih_n ; aNh = h.Whh_n
// n = tanh(aNi + bI_n + r*(aNh + bH_n))   [PyTorch gate order r,z,n]
// ---------------------------------------------------------------------------
__global__ __launch_bounds__(256) void gru_fused(const unsigned short* __restrict__ xbf,
                                                 const unsigned short* __restrict__ hbf,
                                                 const float* __restrict__ w_ih,
                                                 const float* __restrict__ w_hh,
                                                 const float* __restrict__ b_ih,
                                                 const float* __restrict__ b_hh,
                                                 const float* __restrict__ h_prev,
                                                 float* __restrict__ h_out,
                                                 unsigned short* __restrict__ h_bf, int bf_ld) {
  __shared__ unsigned short xa[2][64 * 64];
  __shared__ unsigned short ha[2][64 * 64];
  __shared__ unsigned short wl[2][96 * 64];

  const int tid = threadIdx.x;
  const int wave = tid >> 6, lane = tid & 63;
  const int quad = lane >> 4, l16 = lane & 15;
  const int j0 = blockIdx.x * 16, m0 = blockIdx.y * 64;

  f32x4 wv[6];

  auto stageAB = [&](int k0, int buf) {
    const unsigned short* src = (wave < 2) ? xbf : hbf;
    unsigned short* dst = (wave < 2) ? xa[buf] : ha[buf];
#pragma unroll
    for (int i = 0; i < 4; ++i) {
      int chunk = ((wave & 1) * 4 + i) * 64 + lane;  // 512 = 64 rows x 8 chunks
      int r = chunk >> 3;
      int c = (chunk & 7) ^ (r & 7);
      async16(src + (size_t)(m0 + r) * 1024 + k0 + c * 8, dst + chunk * 8);
    }
  };
  auto loadW = [&](int k0) {
#pragma unroll
    for (int i = 0; i < 6; ++i) {
      int cid = tid + i * 256;
      int rr = cid >> 4, kq = cid & 15;
      int g = rr >> 4, jj = rr & 15;
      const float* Wp = (g < 3) ? w_ih : w_hh;
      int gate = (g < 3) ? g : g - 3;
      wv[i] = *(const f32x4*)(Wp + (size_t)(gate * 1024 + j0 + jj) * 1024 + k0 + kq * 4);
    }
  };
  auto writeW = [&](int buf) {
#pragma unroll
    for (int i = 0; i < 6; ++i) {
      int cid = tid + i * 256;
      int rr = cid >> 4, kq = cid & 15;
      int cq = kq >> 1, half = kq & 1;
      uint2 pk{pack2(wv[i].x, wv[i].y), pack2(wv[i].z, wv[i].w)};
      *(uint2*)&wl[buf][(rr * 8 + (cq ^ (rr & 7))) * 8 + half * 4] = pk;
    }
  };

  f32x4 aR = {0.f, 0.f, 0.f, 0.f}, aZ = {0.f, 0.f, 0.f, 0.f};
  f32x4 aNi = {0.f, 0.f, 0.f, 0.f}, aNh = {0.f, 0.f, 0.f, 0.f};

  stageAB(0, 0);
  loadW(0);
  writeW(0);
  __syncthreads();

  for (int ki = 0; ki < 16; ++ki) {
    const int cur = ki & 1;
    const bool more = (ki < 15);
    if (more) {
      stageAB((ki + 1) * 64, cur ^ 1);
      loadW((ki + 1) * 64);
    }
#pragma unroll
    for (int kh = 0; kh < 2; ++kh) {
      const int c = kh * 4 + quad;
      const int mloc = wave * 16 + l16;
      bf16x8 ax = ldsFrag(&xa[cur][(mloc * 8 + (c ^ (mloc & 7))) * 8]);
      bf16x8 ah = ldsFrag(&ha[cur][(mloc * 8 + (c ^ (mloc & 7))) * 8]);
      bf16x8 wf[6];
#pragma unroll
      for (int g = 0; g < 6; ++g)
        wf[g] = ldsFrag(&wl[cur][((g * 16 + l16) * 8 + (c ^ (l16 & 7))) * 8]);
      aR = __builtin_amdgcn_mfma_f32_16x16x32_bf16(ax, wf[0], aR, 0, 0, 0);
      aZ = __builtin_amdgcn_mfma_f32_16x16x32_bf16(ax, wf[1], aZ, 0, 0, 0);
      aNi = __builtin_amdgcn_mfma_f32_16x16x32_bf16(ax, wf[2], aNi, 0, 0, 0);
      aR = __builtin_amdgcn_mfma_f32_16x16x32_bf16(ah, wf[3], aR, 0, 0, 0);
      aZ = __builtin_amdgcn_mfma_f32_16x16x32_bf16(ah, wf[4], aZ, 0, 0, 0);
      aNh = __builtin_amdgcn_mfma_f32_16x16x32_bf16(ah, wf[5], aNh, 0, 0, 0);
    }
    if (more) writeW(cur ^ 1);
    __syncthreads();
  }

  const int j = j0 + l16;
  const float bIr = b_ih[j], bHr = b_hh[j];
  const float bIz = b_ih[1024 + j], bHz = b_hh[1024 + j];
  const float bIn = b_ih[2048 + j], bHn = b_hh[2048 + j];
#pragma unroll
  for (int r = 0; r < 4; ++r) {
    int m = m0 + wave * 16 + quad * 4 + r;
    float rg = 1.f / (1.f + __expf(-(aR[r] + bIr + bHr)));
    float zg = 1.f / (1.f + __expf(-(aZ[r] + bIz + bHz)));
    float ng = tanhf(aNi[r] + bIn + rg * (aNh[r] + bHn));
    float hp = h_prev[(size_t)m * 1024 + j];
    float ho = (1.f - zg) * ng + zg * hp;
    h_out[(size_t)m * 1024 + j] = ho;
    h_bf[(size_t)m * bf_ld + j] = f2bf(ho);
  }
}

// ---------------------------------------------------------------------------
// prep (blocks 0..383): bf16 copies of embed[ids], hidden[0], hidden[1]
// u2 (blocks 384..399): u2[e] = sum_h v[h]*W_attn[h,1024+e]  (no atomics)
// ---------------------------------------------------------------------------
__global__ __launch_bounds__(256) void prep_u2(const int* __restrict__ ids,
                                               const float* __restrict__ hidden,
                                               const float* __restrict__ embed,
                                               const float* __restrict__ W_attn,
                                               const float* __restrict__ v,
                                               unsigned short* A0, unsigned short* Hh0,
                                               unsigned short* Hh1, float* __restrict__ u2) {
  int blk = blockIdx.x, t = threadIdx.x;
  if (blk < 384) {
    int job = blk >> 7, m = blk & 127;
    const float* src;
    unsigned short* dst;
    if (job == 0) { src = embed + (size_t)ids[m] * 1024; dst = A0; }
    else if (job == 1) { src = hidden + (size_t)m * 1024; dst = Hh0; }
    else { src = hidden + 131072 + (size_t)m * 1024; dst = Hh1; }
    f32x4 val = ((const f32x4*)src)[t];
    uint2 pk{pack2(val.x, val.y), pack2(val.z, val.w)};
    *(uint2*)(dst + (size_t)m * 1024 + t * 4) = pk;
  } else {
    __shared__ float red[4][64];
    int lb = blk - 384;            // 0..15
    int wv_ = t >> 6, l = t & 63;
    int e = lb * 64 + l;
    const float* col = W_attn + 1024 + e;
    float acc = 0.f;
    int h0 = wv_ * 256;
#pragma unroll 8
    for (int h = h0; h < h0 + 256; ++h) acc += v[h] * col[(size_t)h * 2048];
    red[wv_][l] = acc;
    __syncthreads();
    if (t < 64) u2[lb * 64 + t] = red[0][t] + red[1][t] + red[2][t] + red[3][t];
  }
}

// ---------------------------------------------------------------------------
// scores_t[b,s] = enc[s,b,:] . u2 ; 2048 blocks, 16 f32x4 loads batched/wave
// ---------------------------------------------------------------------------
__global__ __launch_bounds__(256) void scores_kernel(const float* __restrict__ enc,
                                                     const float* __restrict__ u2,
                                                     float* __restrict__ sct) {
  int wave = threadIdx.x >> 6, lane = threadIdx.x & 63;
  const f32x4* u4 = (const f32x4*)u2;
  f32x4 uv[4];
#pragma unroll
  for (int p = 0; p < 4; ++p) uv[p] = u4[p * 64 + lane];
  int row0 = (blockIdx.x * 4 + wave) * 4;
  const f32x4* base = (const f32x4*)enc;
  f32x4 ev[4][4];
#pragma unroll
  for (int r = 0; r < 4; ++r)
#pragma unroll
    for (int p = 0; p < 4; ++p) ev[r][p] = base[(size_t)(row0 + r) * 256 + p * 64 + lane];
  float a[4];
#pragma unroll
  for (int r = 0; r < 4; ++r) {
    float s = 0.f;
#pragma unroll
    for (int p = 0; p < 4; ++p)
      s += ev[r][p].x * uv[p].x + ev[r][p].y * uv[p].y + ev[r][p].z * uv[p].z + ev[r][p].w * uv[p].w;
    a[r] = s;
  }
#pragma unroll
  for (int r = 0; r < 4; ++r)
#pragma unroll
    for (int off = 32; off > 0; off >>= 1) a[r] += __shfl_down(a[r], off, 64);
  if (lane == 0) {
#pragma unroll
    for (int r = 0; r < 4; ++r) {
      int row = row0 + r;  // row = s*128 + b
      sct[(row & 127) * 256 + (row >> 7)] = a[r];
    }
  }
}

// ---------------------------------------------------------------------------
// softmax (replicated per h-chunk) + context -> bf16 catin[:,1024+h]
// grid 512 = 128 b x 4 h-chunks; hc==0 writes attn output
// ---------------------------------------------------------------------------
__global__ __launch_bounds__(256) void ctx_softmax(const float* __restrict__ enc,
                                                   const float* __restrict__ sct,
                                                   float* __restrict__ attn,
                                                   unsigned short* __restrict__ catin) {
  __shared__ float sm[256];
  __shared__ float wred[8];
  int b = blockIdx.x >> 2, hc = blockIdx.x & 3, t = threadIdx.x;
  int wv_ = t >> 6, l = t & 63;

  float sc = sct[b * 256 + t];
  float mx = sc;
#pragma unroll
  for (int off = 32; off > 0; off >>= 1) mx = fmaxf(mx, __shfl_xor(mx, off, 64));
  if (l == 0) wred[wv_] = mx;
  __syncthreads();
  float m4 = fmaxf(fmaxf(wred[0], wred[1]), fmaxf(wred[2], wred[3]));
  float e = __expf(sc - m4);
  float s = e;
#pragma unroll
  for (int off = 32; off > 0; off >>= 1) s += __shfl_xor(s, off, 64);
  if (l == 0) wred[4 + wv_] = s;
  __syncthreads();
  float tot = (wred[4] + wred[5]) + (wred[6] + wred[7]);
  float aw = e / tot;
  sm[t] = aw;
  if (hc == 0) attn[b * 256 + t] = aw;
  __syncthreads();

  int h = hc * 256 + t;
  const float* ep = enc + (size_t)b * 1024 + h;
  float a[16];
#pragma unroll
  for (int i = 0; i < 16; ++i) a[i] = 0.f;
  for (int s0 = 0; s0 < 256; s0 += 16)
#pragma unroll
    for (int i = 0; i < 16; ++i) a[i] += sm[s0 + i] * ep[(size_t)(s0 + i) * 131072];
  float ctx = 0.f;
#pragma unroll
  for (int i = 0; i < 16; ++i) ctx += a[i];
  catin[(size_t)b * 2048 + 1024 + h] = f2bf(ctx);
}

// ---------------------------------------------------------------------------
extern "C" void kernel_launch(void* const* d_in, const int* in_sizes, int n_in,
                              void* d_out_, int out_size, void* d_ws, size_t ws_size,
                              hipStream_t stream) {
  const int* ids = (const int*)d_in[0];
  const float* hidden = (const float*)d_in[1];
  const float* enc = (const float*)d_in[2];
  const float* embed = (const float*)d_in[3];
  const float* W_attn = (const float*)d_in[4];
  const float* v = (const float*)d_in[6];
  const float* w_ih0 = (const float*)d_in[7];
  const float* w_hh0 = (const float*)d_in[8];
  const float* b_ih0 = (const float*)d_in[9];
  const float* b_hh0 = (const float*)d_in[10];
  const float* w_ih1 = (const float*)d_in[11];
  const float* w_hh1 = (const float*)d_in[12];
  const float* b_ih1 = (const float*)d_in[13];
  const float* b_hh1 = (const float*)d_in[14];
  const float* W_cat = (const float*)d_in[15];
  const float* b_cat = (const float*)d_in[16];
  const float* W_out = (const float*)d_in[17];
  const float* b_out = (const float*)d_in[18];

  float* out = (float*)d_out_;
  float* h0 = out + 4096000;
  float* h1 = out + 4227072;
  float* attn = out + 4358144;

  float* ws = (float*)d_ws;
  float* u2 = ws;                          // 1024
  float* sct = ws + 1024;                  // 32768
  unsigned short* bfb = (unsigned short*)(ws + 1024 + 32768);
  unsigned short* A0 = bfb;                // 131072
  unsigned short* Hh0 = bfb + 131072;
  unsigned short* Hh1 = bfb + 262144;
  unsigned short* h0bf = bfb + 393216;
  unsigned short* catin = bfb + 524288;    // 128 x 2048
  unsigned short* catbf = bfb + 786432;    // 128 x 1024

  // 1: bf16 prep + u2 reduction
  prep_u2<<<400, 256, 0, stream>>>(ids, hidden, embed, W_attn, v, A0, Hh0, Hh1, u2);
  // 2: attention scores (streaming GEMV over enc)
  scores_kernel<<<2048, 256, 0, stream>>>(enc, u2, sct);
  // 3: softmax + context (writes attn output + catin right half)
  ctx_softmax<<<512, 256, 0, stream>>>(enc, sct, attn, catin);
  // 4-5: fused GRU layers (GEMM + gates in one kernel each)
  gru_fused<<<dim3(64, 2), 256, 0, stream>>>(A0, Hh0, w_ih0, w_hh0, b_ih0, b_hh0,
                                             hidden, h0, h0bf, 1024);
  gru_fused<<<dim3(64, 2), 256, 0, stream>>>(h0bf, Hh1, w_ih1, w_hh1, b_ih1, b_hh1,
                                             hidden + 131072, h1, catin, 2048);
  // 6: concat GEMM with fused tanh->bf16 epilogue
  gemm_bt<16, 4, 1, 1><<<64, 256, 0, stream>>>(catin, W_cat, b_cat, catbf, 2048, 2048, 1024, 2048);
  // 7: output GEMM
  gemm_bt<32, 2, 2, 0><<<1000, 256, 0, stream>>>(catbf, W_out, b_out, out, 1024, 1024, 32000, 1024);
}

// Round 4
// 494.584 us; speedup vs baseline: 1.0722x; 1.0722x over previous
//
#include <hip/hip_runtime.h>
#include <cstdint>
#include <cstddef>

typedef __attribute__((ext_vector_type(4))) float f32x4;
typedef __attribute__((ext_vector_type(8))) __bf16 bf16x8;
typedef __attribute__((ext_vector_type(8))) short short8;

__device__ __forceinline__ unsigned short f2bf(float f) {
  unsigned u = __builtin_bit_cast(unsigned, f);
  u += 0x7FFFu + ((u >> 16) & 1u);  // RNE
  return (unsigned short)(u >> 16);
}
__device__ __forceinline__ unsigned pack2(float a, float b) {
  return (unsigned)f2bf(a) | ((unsigned)f2bf(b) << 16);
}
__device__ __forceinline__ void async16(const void* g, void* l) {
  __builtin_amdgcn_global_load_lds((const __attribute__((address_space(1))) unsigned int*)g,
                                   (__attribute__((address_space(3))) unsigned int*)l, 16, 0, 0);
}
__device__ __forceinline__ bf16x8 ldsFrag(const unsigned short* p) {
  return __builtin_bit_cast(bf16x8, *(const short8*)p);
}

struct GemmArgs {
  const unsigned short* A;  // bf16 [128, lda]
  const float* W;           // fp32 [N, ldw]
  const float* bias;        // [N]
  float* C;                 // fp32 [128, N] (+ kseg*seg_stride)
};

// ---------------------------------------------------------------------------
// GEMM body: C[128, n-tile] = A[128,Kseg]@W^T (+bias if addbias)
// A: async global_load_lds, XOR-swizzled 16B chunks, double-buffered dist-1.
// W: dist-2 register prefetch -> bf16 -> LDS double buffer.
// ---------------------------------------------------------------------------
template <int BN, int WAVES_M, int WAVES_N>
__device__ __forceinline__ void gemm_body(const unsigned short* __restrict__ A,
                                          const float* __restrict__ W,
                                          const float* __restrict__ bias,
                                          float* __restrict__ Cout, int lda, int ldw, int N,
                                          int Kseg, int kbase, int nblk, bool addbias,
                                          unsigned short* a_lds, unsigned short* w_lds) {
  constexpr int WM = 128 / WAVES_M, WN = BN / WAVES_N;
  constexpr int MT = WM / 16, NT = WN / 16;
  constexpr int WCH = (BN == 32) ? 2 : 1;

  const int tid = threadIdx.x;
  const int wave = tid >> 6, lane = tid & 63;
  const int quad = lane >> 4, l16 = lane & 15;
  const int n0 = nblk * BN;
  const int wm = (wave / WAVES_N) * WM, wn = (wave % WAVES_N) * WN;
  const int niter = Kseg >> 6;

  f32x4 wv[2][WCH];

  auto stageA = [&](int k0, int buf) {
#pragma unroll
    for (int i = 0; i < 4; ++i) {
      int chunk = (wave * 4 + i) * 64 + lane;  // 1024 = 128 rows x 8 chunks
      int r = chunk >> 3;
      int c = (chunk & 7) ^ (r & 7);
      async16(A + (size_t)r * lda + k0 + c * 8, a_lds + (size_t)buf * 8192 + chunk * 8);
    }
  };
  auto loadW = [&](int k0, int set) {
    if constexpr (BN == 32) {
      const float* p = W + (size_t)(n0 + (tid >> 3)) * ldw + k0 + (tid & 7) * 8;
      wv[set][0] = *(const f32x4*)p;
      wv[set][1] = *(const f32x4*)(p + 4);
    } else {
      const float* p = W + (size_t)(n0 + (tid >> 4)) * ldw + k0 + ((tid >> 1) & 7) * 8 + (tid & 1) * 4;
      wv[set][0] = *(const f32x4*)p;
    }
  };
  auto writeW = [&](int set, int buf) {
    unsigned short* wb = w_lds + (size_t)buf * BN * 64;
    if constexpr (BN == 32) {
      int wr = tid >> 3, wc = tid & 7;
      uint4 pk{pack2(wv[set][0].x, wv[set][0].y), pack2(wv[set][0].z, wv[set][0].w),
               pack2(wv[set][1].x, wv[set][1].y), pack2(wv[set][1].z, wv[set][1].w)};
      *(uint4*)&wb[(wr * 8 + (wc ^ (wr & 7))) * 8] = pk;
    } else {
      int wr = tid >> 4, wc = (tid >> 1) & 7, half = tid & 1;
      uint2 pk{pack2(wv[set][0].x, wv[set][0].y), pack2(wv[set][0].z, wv[set][0].w)};
      *(uint2*)&wb[(wr * 8 + (wc ^ (wr & 7))) * 8 + half * 4] = pk;
    }
  };

  f32x4 acc[MT][NT] = {};

  loadW(kbase, 0);
  stageA(kbase, 0);
  loadW(kbase + 64, 1);
  writeW(0, 0);
  __syncthreads();

  for (int ki = 0; ki < niter; ++ki) {
    const int cur = ki & 1;
    if (ki + 1 < niter) stageA(kbase + (ki + 1) * 64, cur ^ 1);
    if (ki + 2 < niter) loadW(kbase + (ki + 2) * 64, cur);
#pragma unroll
    for (int kh = 0; kh < 2; ++kh) {
      const int c = kh * 4 + quad;
      const unsigned short* ab = a_lds + (size_t)cur * 8192;
      const unsigned short* wb = w_lds + (size_t)cur * BN * 64;
      bf16x8 af[MT], wf[NT];
#pragma unroll
      for (int mt = 0; mt < MT; ++mt) {
        int m = wm + mt * 16 + l16;
        af[mt] = ldsFrag(&ab[(m * 8 + (c ^ (m & 7))) * 8]);
      }
#pragma unroll
      for (int nt = 0; nt < NT; ++nt) {
        int n = wn + nt * 16 + l16;
        wf[nt] = ldsFrag(&wb[(n * 8 + (c ^ (n & 7))) * 8]);
      }
#pragma unroll
      for (int mt = 0; mt < MT; ++mt)
#pragma unroll
        for (int nt = 0; nt < NT; ++nt)
          acc[mt][nt] = __builtin_amdgcn_mfma_f32_16x16x32_bf16(af[mt], wf[nt], acc[mt][nt], 0, 0, 0);
    }
    if (ki + 1 < niter) writeW(cur ^ 1, cur ^ 1);
    __syncthreads();
  }

#pragma unroll
  for (int mt = 0; mt < MT; ++mt)
#pragma unroll
    for (int nt = 0; nt < NT; ++nt) {
      int n = n0 + wn + nt * 16 + l16;
      float bv = addbias ? bias[n] : 0.f;
#pragma unroll
      for (int r = 0; r < 4; ++r) {
        int m = wm + mt * 16 + quad * 4 + r;
        Cout[(size_t)m * N + n] = acc[mt][nt][r] + bv;
      }
    }
}

// standalone GEMM kernel: grid (ntiles, pair, ksplit)
template <int BN, int WAVES_M, int WAVES_N>
__global__ __launch_bounds__(256, 4) void gemm_k(GemmArgs g0, GemmArgs g1, int lda, int ldw,
                                                 int N, int Kseg, int seg_stride) {
  __shared__ unsigned short a_lds[2 * 128 * 64];
  __shared__ unsigned short w_lds[2 * BN * 64];
  const GemmArgs g = (blockIdx.y == 0) ? g0 : g1;
  const int kseg = blockIdx.z;
  gemm_body<BN, WAVES_M, WAVES_N>(g.A, g.W, g.bias, g.C + (size_t)kseg * seg_stride, lda, ldw,
                                  N, Kseg, kseg * Kseg, blockIdx.x, kseg == 0, a_lds, w_lds);
}

// ---------------------------------------------------------------------------
// scores body: sct[b,s] = enc[s,b,:] . u2   (bx in [0,2048))
// ---------------------------------------------------------------------------
__device__ __forceinline__ void scores_body(int bx, const float* __restrict__ enc,
                                            const float* __restrict__ u2,
                                            float* __restrict__ sct) {
  int wave = threadIdx.x >> 6, lane = threadIdx.x & 63;
  const f32x4* u4 = (const f32x4*)u2;
  f32x4 uv[4];
#pragma unroll
  for (int p = 0; p < 4; ++p) uv[p] = u4[p * 64 + lane];
  int row0 = (bx * 4 + wave) * 4;
  const f32x4* base = (const f32x4*)enc;
  f32x4 ev[4][4];
#pragma unroll
  for (int r = 0; r < 4; ++r)
#pragma unroll
    for (int p = 0; p < 4; ++p) ev[r][p] = base[(size_t)(row0 + r) * 256 + p * 64 + lane];
  float a[4];
#pragma unroll
  for (int r = 0; r < 4; ++r) {
    float s = 0.f;
#pragma unroll
    for (int p = 0; p < 4; ++p)
      s += ev[r][p].x * uv[p].x + ev[r][p].y * uv[p].y + ev[r][p].z * uv[p].z + ev[r][p].w * uv[p].w;
    a[r] = s;
  }
#pragma unroll
  for (int r = 0; r < 4; ++r)
#pragma unroll
    for (int off = 32; off > 0; off >>= 1) a[r] += __shfl_down(a[r], off, 64);
  if (lane == 0) {
#pragma unroll
    for (int r = 0; r < 4; ++r) {
      int row = row0 + r;  // row = s*128 + b
      sct[(row & 127) * 256 + (row >> 7)] = a[r];
    }
  }
}

// ---------------------------------------------------------------------------
// mega_sg: blocks [0,2048) scores  ||  [2048,2816) GRU0 GEMM (BN=16, splitK=2)
// ---------------------------------------------------------------------------
__global__ __launch_bounds__(256, 4) void mega_sg(const float* __restrict__ enc,
                                                  const float* __restrict__ u2,
                                                  float* __restrict__ sct, GemmArgs g0,
                                                  GemmArgs g1, int lda, int ldw, int N, int Kseg,
                                                  int seg_stride) {
  __shared__ unsigned short a_lds[2 * 128 * 64];
  __shared__ unsigned short w_lds[2 * 16 * 64];
  int bx = blockIdx.x;
  if (bx < 2048) {
    scores_body(bx, enc, u2, sct);
    return;
  }
  int idx = bx - 2048;
  int nt = idx % 192;
  int pair = (idx / 192) & 1;
  int kseg = idx / 384;
  const GemmArgs g = pair ? g1 : g0;
  gemm_body<16, 4, 1>(g.A, g.W, g.bias, g.C + (size_t)kseg * seg_stride, lda, ldw, N, Kseg,
                      kseg * Kseg, nt, kseg == 0, a_lds, w_lds);
}

// ---------------------------------------------------------------------------
// ctx body: softmax over s (replicated per h-chunk) + context -> catin right half
// ---------------------------------------------------------------------------
__device__ __forceinline__ void ctx_body(int bx, const float* __restrict__ enc,
                                         const float* __restrict__ sct, float* __restrict__ attn,
                                         unsigned short* __restrict__ catin) {
  __shared__ float sm[256];
  __shared__ float wred[8];
  int b = bx >> 2, hc = bx & 3, t = threadIdx.x;
  int wv_ = t >> 6, l = t & 63;

  float sc = sct[b * 256 + t];
  float mx = sc;
#pragma unroll
  for (int off = 32; off > 0; off >>= 1) mx = fmaxf(mx, __shfl_xor(mx, off, 64));
  if (l == 0) wred[wv_] = mx;
  __syncthreads();
  float m4 = fmaxf(fmaxf(wred[0], wred[1]), fmaxf(wred[2], wred[3]));
  float e = __expf(sc - m4);
  float s = e;
#pragma unroll
  for (int off = 32; off > 0; off >>= 1) s += __shfl_xor(s, off, 64);
  if (l == 0) wred[4 + wv_] = s;
  __syncthreads();
  float tot = (wred[4] + wred[5]) + (wred[6] + wred[7]);
  float aw = e / tot;
  sm[t] = aw;
  if (hc == 0) attn[b * 256 + t] = aw;
  __syncthreads();

  int h = hc * 256 + t;
  const float* ep = enc + (size_t)b * 1024 + h;
  float a[16];
#pragma unroll
  for (int i = 0; i < 16; ++i) a[i] = 0.f;
  for (int s0 = 0; s0 < 256; s0 += 16)
#pragma unroll
    for (int i = 0; i < 16; ++i) a[i] += sm[s0 + i] * ep[(size_t)(s0 + i) * 131072];
  float ctx = 0.f;
#pragma unroll
  for (int i = 0; i < 16; ++i) ctx += a[i];
  catin[(size_t)b * 2048 + 1024 + h] = f2bf(ctx);
}

// ---------------------------------------------------------------------------
// gate body: sums 2 split-K partials of gi/gh, GRU gate math, fp32 + bf16 out
// ---------------------------------------------------------------------------
__device__ __forceinline__ void gate_body(int b, const float* __restrict__ gi,
                                          const float* __restrict__ gh,
                                          const float* __restrict__ h_prev,
                                          float* __restrict__ h_out,
                                          unsigned short* __restrict__ h_bf, int bf_ld) {
  constexpr int SEG = 393216;
  int j = threadIdx.x * 4;
  const float* gib = gi + (size_t)b * 3072;
  const float* ghb = gh + (size_t)b * 3072;
  f32x4 ir = *(const f32x4*)(gib + j) + *(const f32x4*)(gib + SEG + j);
  f32x4 iz = *(const f32x4*)(gib + 1024 + j) + *(const f32x4*)(gib + SEG + 1024 + j);
  f32x4 in_ = *(const f32x4*)(gib + 2048 + j) + *(const f32x4*)(gib + SEG + 2048 + j);
  f32x4 hr = *(const f32x4*)(ghb + j) + *(const f32x4*)(ghb + SEG + j);
  f32x4 hz = *(const f32x4*)(ghb + 1024 + j) + *(const f32x4*)(ghb + SEG + 1024 + j);
  f32x4 hn = *(const f32x4*)(ghb + 2048 + j) + *(const f32x4*)(ghb + SEG + 2048 + j);
  f32x4 hp = *(const f32x4*)(h_prev + (size_t)b * 1024 + j);
  f32x4 ho;
#pragma unroll
  for (int c = 0; c < 4; ++c) {
    float r = 1.f / (1.f + __expf(-(ir[c] + hr[c])));
    float z = 1.f / (1.f + __expf(-(iz[c] + hz[c])));
    float n = tanhf(in_[c] + r * hn[c]);
    ho[c] = (1.f - z) * n + z * hp[c];
  }
  *(f32x4*)(h_out + (size_t)b * 1024 + j) = ho;
  uint2 pk{pack2(ho.x, ho.y), pack2(ho.z, ho.w)};
  *(uint2*)(h_bf + (size_t)b * bf_ld + j) = pk;
}

// mega_cg: blocks [0,512) ctx_softmax || [512,640) GRU0 gate
__global__ __launch_bounds__(256) void mega_cg(const float* __restrict__ enc,
                                               const float* __restrict__ sct,
                                               float* __restrict__ attn,
                                               unsigned short* __restrict__ catin,
                                               const float* __restrict__ gi,
                                               const float* __restrict__ gh,
                                               const float* __restrict__ h_prev,
                                               float* __restrict__ h_out,
                                               unsigned short* __restrict__ h_bf, int bf_ld) {
  int bx = blockIdx.x;
  if (bx < 512) ctx_body(bx, enc, sct, attn, catin);
  else gate_body(bx - 512, gi, gh, h_prev, h_out, h_bf, bf_ld);
}

__global__ __launch_bounds__(256) void gate_k(const float* __restrict__ gi,
                                              const float* __restrict__ gh,
                                              const float* __restrict__ h_prev,
                                              float* __restrict__ h_out,
                                              unsigned short* __restrict__ h_bf, int bf_ld) {
  gate_body(blockIdx.x, gi, gh, h_prev, h_out, h_bf, bf_ld);
}

// ---------------------------------------------------------------------------
// prep (blocks 0..383): bf16 copies of embed[ids], hidden[0], hidden[1]
// u2 (blocks 384..399): u2[e] = sum_h v[h]*W_attn[h,1024+e]
// ---------------------------------------------------------------------------
__global__ __launch_bounds__(256) void prep_u2(const int* __restrict__ ids,
                                               const float* __restrict__ hidden,
                                               const float* __restrict__ embed,
                                               const float* __restrict__ W_attn,
                                               const float* __restrict__ v,
                                               unsigned short* A0, unsigned short* Hh0,
                                               unsigned short* Hh1, float* __restrict__ u2) {
  int blk = blockIdx.x, t = threadIdx.x;
  if (blk < 384) {
    int job = blk >> 7, m = blk & 127;
    const float* src;
    unsigned short* dst;
    if (job == 0) { src = embed + (size_t)ids[m] * 1024; dst = A0; }
    else if (job == 1) { src = hidden + (size_t)m * 1024; dst = Hh0; }
    else { src = hidden + 131072 + (size_t)m * 1024; dst = Hh1; }
    f32x4 val = ((const f32x4*)src)[t];
    uint2 pk{pack2(val.x, val.y), pack2(val.z, val.w)};
    *(uint2*)(dst + (size_t)m * 1024 + t * 4) = pk;
  } else {
    __shared__ float red[4][64];
    int lb = blk - 384;  // 0..15
    int wv_ = t >> 6, l = t & 63;
    int e = lb * 64 + l;
    const float* col = W_attn + 1024 + e;
    float acc = 0.f;
    int h0 = wv_ * 256;
#pragma unroll 8
    for (int h = h0; h < h0 + 256; ++h) acc += v[h] * col[(size_t)h * 2048];
    red[wv_][l] = acc;
    __syncthreads();
    if (t < 64) u2[lb * 64 + t] = red[0][t] + red[1][t] + red[2][t] + red[3][t];
  }
}

// cat_fix: sum 4 split-K partials (bias in seg0), tanh, bf16
__global__ __launch_bounds__(256) void cat_fix(const float* __restrict__ part,
                                               unsigned short* __restrict__ catbf) {
  int m = blockIdx.x, j = threadIdx.x * 4;
  const float* p = part + (size_t)m * 1024 + j;
  f32x4 s = *(const f32x4*)p + *(const f32x4*)(p + 131072) + *(const f32x4*)(p + 262144) +
            *(const f32x4*)(p + 393216);
  f32x4 o;
#pragma unroll
  for (int c = 0; c < 4; ++c) o[c] = tanhf(s[c]);
  uint2 pk{pack2(o.x, o.y), pack2(o.z, o.w)};
  *(uint2*)(catbf + (size_t)m * 1024 + j) = pk;
}

// ---------------------------------------------------------------------------
extern "C" void kernel_launch(void* const* d_in, const int* in_sizes, int n_in,
                              void* d_out_, int out_size, void* d_ws, size_t ws_size,
                              hipStream_t stream) {
  const int* ids = (const int*)d_in[0];
  const float* hidden = (const float*)d_in[1];
  const float* enc = (const float*)d_in[2];
  const float* embed = (const float*)d_in[3];
  const float* W_attn = (const float*)d_in[4];
  const float* v = (const float*)d_in[6];
  const float* w_ih0 = (const float*)d_in[7];
  const float* w_hh0 = (const float*)d_in[8];
  const float* b_ih0 = (const float*)d_in[9];
  const float* b_hh0 = (const float*)d_in[10];
  const float* w_ih1 = (const float*)d_in[11];
  const float* w_hh1 = (const float*)d_in[12];
  const float* b_ih1 = (const float*)d_in[13];
  const float* b_hh1 = (const float*)d_in[14];
  const float* W_cat = (const float*)d_in[15];
  const float* b_cat = (const float*)d_in[16];
  const float* W_out = (const float*)d_in[17];
  const float* b_out = (const float*)d_in[18];

  float* out = (float*)d_out_;
  float* h0 = out + 4096000;
  float* h1 = out + 4227072;
  float* attn = out + 4358144;

  float* ws = (float*)d_ws;
  float* gi = ws;                    // 2 segs x 393216
  float* gh = ws + 786432;           // 2 segs x 393216
  float* u2 = ws + 1572864;          // 1024
  float* sct = ws + 1573888;         // 32768
  float* catp = ws + 1606656;        // 4 x 131072
  unsigned short* bfb = (unsigned short*)(ws + 2130944);
  unsigned short* A0 = bfb;              // 131072
  unsigned short* Hh0 = bfb + 131072;
  unsigned short* Hh1 = bfb + 262144;
  unsigned short* h0bf = bfb + 393216;
  unsigned short* catin = bfb + 524288;  // 128 x 2048
  unsigned short* catbf = bfb + 786432;  // 128 x 1024

  // 1: bf16 prep + u2 reduction
  prep_u2<<<400, 256, 0, stream>>>(ids, hidden, embed, W_attn, v, A0, Hh0, Hh1, u2);

  // 2: scores || GRU0 GEMM (split-K=2, 768 blocks)
  {
    GemmArgs ai{A0, w_ih0, b_ih0, gi}, ah{Hh0, w_hh0, b_hh0, gh};
    mega_sg<<<2816, 256, 0, stream>>>(enc, u2, sct, ai, ah, 1024, 1024, 3072, 512, 393216);
  }

  // 3: ctx_softmax || GRU0 gate
  mega_cg<<<640, 256, 0, stream>>>(enc, sct, attn, catin, gi, gh, hidden, h0, h0bf, 1024);

  // 4: GRU1 GEMM
  {
    GemmArgs ai{h0bf, w_ih1, b_ih1, gi}, ah{Hh1, w_hh1, b_hh1, gh};
    gemm_k<16, 4, 1><<<dim3(192, 2, 2), 256, 0, stream>>>(ai, ah, 1024, 1024, 3072, 512, 393216);
  }

  // 5: GRU1 gate (h1 -> output + catin left half)
  gate_k<<<128, 256, 0, stream>>>(gi, gh, hidden + 131072, h1, catin, 2048);

  // 6: concat GEMM (split-K=4)
  {
    GemmArgs ac{catin, W_cat, b_cat, catp}, dummy = ac;
    gemm_k<16, 4, 1><<<dim3(64, 1, 4), 256, 0, stream>>>(ac, dummy, 2048, 2048, 1024, 512, 131072);
  }

  // 7: sum partials + tanh -> bf16
  cat_fix<<<128, 256, 0, stream>>>(catp, catbf);

  // 8: output GEMM
  {
    GemmArgs ao{catbf, W_out, b_out, out}, dummy = ao;
    gemm_k<32, 2, 2><<<dim3(1000, 1, 1), 256, 0, stream>>>(ao, dummy, 1024, 1024, 32000, 1024, 0);
  }
}